// Round 5
// baseline (856.055 us; speedup 1.0000x reference)
//
#include <hip/hip_runtime.h>
#include <math.h>

#define TPB 256
#define CHUNK 1024   // elements per scan block
// bins are 64 consecutive nodes: bin = dst >> 6, rel = dst & 63 (packed unsigned in bits 26..31)

// ---------------------------------------------------------------------------
// Phase 0: CSR-by-dst build (once per call, shared by all 4 layers)
// ---------------------------------------------------------------------------
__global__ void count_kernel(const int* __restrict__ dst, int* __restrict__ cnt, int E) {
    int e = blockIdx.x * blockDim.x + threadIdx.x;
    if (e < E) atomicAdd(&cnt[dst[e]], 1);
}

__global__ void partial_kernel(const int* __restrict__ cnt, int* __restrict__ partials, int N) {
    __shared__ int red[TPB];
    int base = blockIdx.x * CHUNK;
    int t = threadIdx.x;
    int s = 0;
    for (int i = t; i < CHUNK; i += TPB) {
        int idx = base + i;
        if (idx < N) s += cnt[idx];
    }
    red[t] = s;
    __syncthreads();
    for (int off = TPB / 2; off > 0; off >>= 1) {
        if (t < off) red[t] += red[t + off];
        __syncthreads();
    }
    if (t == 0) partials[blockIdx.x] = red[0];
}

__global__ void scan_partials_kernel(int* __restrict__ partials, int P) {
    __shared__ int buf[1024];
    int t = threadIdx.x;
    int v = (t < P) ? partials[t] : 0;
    buf[t] = v;
    __syncthreads();
    for (int off = 1; off < 1024; off <<= 1) {
        int u = (t >= off) ? buf[t - off] : 0;
        __syncthreads();
        buf[t] += u;
        __syncthreads();
    }
    if (t < P) partials[t] = buf[t] - v;   // exclusive
}

// writes rowptr AND a cursor copy (cursor used by single-pass fallback fill)
__global__ void rowptr_kernel(const int* __restrict__ cnt, const int* __restrict__ partials,
                              int* __restrict__ rowptr, int* __restrict__ cursor, int N, int E) {
    __shared__ int tsum[TPB];
    int base = blockIdx.x * CHUNK;
    int t = threadIdx.x;
    int idx0 = base + t * 4;
    int c[4];
    int s = 0;
#pragma unroll
    for (int j = 0; j < 4; ++j) {
        int i = idx0 + j;
        c[j] = (i < N) ? cnt[i] : 0;
        s += c[j];
    }
    tsum[t] = s;
    __syncthreads();
    for (int off = 1; off < TPB; off <<= 1) {
        int u = (t >= off) ? tsum[t - off] : 0;
        __syncthreads();
        tsum[t] += u;
        __syncthreads();
    }
    int run = partials[blockIdx.x] + tsum[t] - s;
#pragma unroll
    for (int j = 0; j < 4; ++j) {
        int i = idx0 + j;
        if (i < N) { rowptr[i] = run; cursor[i] = run; run += c[j]; }
    }
    if (blockIdx.x == 0 && t == 0) rowptr[N] = E;
}

__global__ void bincur_kernel(const int* __restrict__ rowptr, int* __restrict__ binCur,
                              int NB, int N) {
    int b = blockIdx.x * blockDim.x + threadIdx.x;
    if (b < NB) binCur[b] = rowptr[min(b << 6, N)];
}

// pass 1: scatter edge -> its 64-node bin region (sequential frontier per bin).
// record = {ea0, ea1, ea2, uint: (rel<<26)|src}   (all-unsigned packing!)
__global__ void pass1_kernel(const int* __restrict__ src, const int* __restrict__ dst,
                             const float* __restrict__ ea, int* __restrict__ binCur,
                             float4* __restrict__ tmp, int E) {
    int e = blockIdx.x * blockDim.x + threadIdx.x;
    if (e >= E) return;
    int d = dst[e];
    int pos = atomicAdd(&binCur[d >> 6], 1);
    float4 p;
    p.x = ea[(size_t)e * 3 + 0];
    p.y = ea[(size_t)e * 3 + 1];
    p.z = ea[(size_t)e * 3 + 2];
    p.w = __uint_as_float((unsigned)src[e] | ((unsigned)(d & 63) << 26));
    tmp[pos] = p;
}

// pass 2: block per bin; permute within bin (L2-resident span) via LDS cursors.
__global__ void pass2_kernel(const int* __restrict__ rowptr, const float4* __restrict__ tmp,
                             float4* __restrict__ perm, int N) {
    __shared__ int lcur[64];
    int n0 = blockIdx.x << 6;
    int n1 = min(n0 + 64, N);
    int t = threadIdx.x;
    if (t < n1 - n0) lcur[t] = rowptr[n0 + t];
    __syncthreads();
    int lo = rowptr[n0], hi = rowptr[n1];
    for (int i = lo + t; i < hi; i += blockDim.x) {
        float4 v = tmp[i];
        unsigned bits = __float_as_uint(v.w);
        int rel = (int)(bits >> 26);                 // logical shift: always 0..63
        unsigned s = bits & ((1u << 26) - 1u);
        int pos = atomicAdd(&lcur[rel], 1);
        v.w = __uint_as_float(s);
        perm[pos] = v;
    }
}

// single-pass fallback fill (used only if ws too small for two-pass buffers)
__global__ void fill_kernel(const int* __restrict__ src, const int* __restrict__ dst,
                            const float* __restrict__ ea, int* __restrict__ cursor,
                            float4* __restrict__ perm, int E) {
    int e = blockIdx.x * blockDim.x + threadIdx.x;
    if (e >= E) return;
    int d = dst[e];
    int pos = atomicAdd(&cursor[d], 1);
    float4 p;
    p.x = ea[(size_t)e * 3 + 0];
    p.y = ea[(size_t)e * 3 + 1];
    p.z = ea[(size_t)e * 3 + 2];
    p.w = __uint_as_float((unsigned)src[e]);
    perm[pos] = p;
}

// ---------------------------------------------------------------------------
// Fused layer: 4 lanes per node. Sufficient statistic T[i][k] = sum_e w_k * h[src][i],
// then out[n,o] = elu( invdeg * sum_{i,k} T[i][k] g[i][k*COUT+o] + h[n]@root + b ).
// ---------------------------------------------------------------------------
template<int CIN, int COUT, bool ELU>
__global__ void layer_kernel(const float* __restrict__ h,
                             const float* __restrict__ g,      // [CIN, 3*COUT]
                             const float* __restrict__ mu, const float* __restrict__ sigma,
                             const float* __restrict__ root,   // [CIN, COUT]
                             const float* __restrict__ bias,
                             const int* __restrict__ rowptr,
                             const float4* __restrict__ perm,
                             float* __restrict__ out, int N) {
    __shared__ float s_g[CIN * 3 * COUT];
    __shared__ float s_root[CIN * COUT];
    __shared__ float s_b[COUT];
    __shared__ float s_mu[9], s_gs[9];
    int t = threadIdx.x;
    for (int i = t; i < CIN * 3 * COUT; i += TPB) s_g[i] = g[i];
    for (int i = t; i < CIN * COUT; i += TPB) s_root[i] = root[i];
    if (t < COUT) s_b[t] = bias[t];
    if (t < 9) {
        s_mu[t] = mu[t];
        float sg = sigma[t];
        s_gs[t] = -0.5f / (1e-15f + sg * sg);
    }
    __syncthreads();

    int gid = blockIdx.x * TPB + t;
    int n = gid >> 2;
    int sub = gid & 3;
    bool active = n < N;

    float T[CIN][3] = {};
    int e0 = 0, e1 = 0;
    if (active) { e0 = rowptr[n]; e1 = rowptr[n + 1]; }

    for (int e = e0 + sub; e < e1; e += 4) {
        float4 p = perm[e];
        unsigned s = __float_as_uint(p.w);
        float w[3];
#pragma unroll
        for (int k = 0; k < 3; ++k) {
            float d0 = p.x - s_mu[3 * k + 0];
            float d1 = p.y - s_mu[3 * k + 1];
            float d2 = p.z - s_mu[3 * k + 2];
            w[k] = __expf(d0 * d0 * s_gs[3 * k + 0] +
                          d1 * d1 * s_gs[3 * k + 1] +
                          d2 * d2 * s_gs[3 * k + 2]);
        }
        const float* hr = h + (size_t)s * CIN;
        float hv[CIN];
        if constexpr (CIN == 3) {
            hv[0] = hr[0]; hv[1] = hr[1]; hv[2] = hr[2];
        } else {
#pragma unroll
            for (int q = 0; q < CIN / 4; ++q) {
                float4 v = ((const float4*)hr)[q];
                hv[4 * q + 0] = v.x; hv[4 * q + 1] = v.y;
                hv[4 * q + 2] = v.z; hv[4 * q + 3] = v.w;
            }
        }
#pragma unroll
        for (int i = 0; i < CIN; ++i) {
            T[i][0] = fmaf(hv[i], w[0], T[i][0]);
            T[i][1] = fmaf(hv[i], w[1], T[i][1]);
            T[i][2] = fmaf(hv[i], w[2], T[i][2]);
        }
    }

    // reduce T across the 4 lanes of this node (lanes consecutive: xor 1, 2)
#pragma unroll
    for (int i = 0; i < CIN; ++i)
#pragma unroll
        for (int k = 0; k < 3; ++k) {
            float v = T[i][k];
            v += __shfl_xor(v, 1);
            v += __shfl_xor(v, 2);
            T[i][k] = v;
        }

    if (active) {
        float invd = 1.0f / fmaxf((float)(e1 - e0), 1.0f);
        const float* hn = h + (size_t)n * CIN;
        float hv2[CIN];
        if constexpr (CIN == 3) {
            hv2[0] = hn[0]; hv2[1] = hn[1]; hv2[2] = hn[2];
        } else {
#pragma unroll
            for (int q = 0; q < CIN / 4; ++q) {
                float4 v = ((const float4*)hn)[q];
                hv2[4 * q + 0] = v.x; hv2[4 * q + 1] = v.y;
                hv2[4 * q + 2] = v.z; hv2[4 * q + 3] = v.w;
            }
        }
#pragma unroll
        for (int j = 0; j < COUT / 4; ++j) {
            int o = sub + 4 * j;
            float acc = 0.f;
#pragma unroll
            for (int i = 0; i < CIN; ++i)
#pragma unroll
                for (int k = 0; k < 3; ++k)
                    acc = fmaf(T[i][k], s_g[(i * 3 + k) * COUT + o], acc);
            acc = acc * invd + s_b[o];
#pragma unroll
            for (int i = 0; i < CIN; ++i)
                acc = fmaf(hv2[i], s_root[i * COUT + o], acc);
            if (ELU && acc < 0.f) acc = __expf(acc) - 1.0f;
            out[(size_t)n * COUT + o] = acc;
        }
    }
}

// ---------------------------------------------------------------------------
template<int CIN, int COUT, bool ELU>
static void launch_layer(const float* hin, const float* g, const float* mu,
                         const float* sigma, const float* root, const float* b,
                         const int* rowptr, const float4* perm,
                         float* hout, int N, hipStream_t stream) {
    int blocks = (N * 4 + TPB - 1) / TPB;
    layer_kernel<CIN, COUT, ELU><<<blocks, TPB, 0, stream>>>(
        hin, g, mu, sigma, root, b, rowptr, perm, hout, N);
}

extern "C" void kernel_launch(void* const* d_in, const int* in_sizes, int n_in,
                              void* d_out, int out_size, void* d_ws, size_t ws_size,
                              hipStream_t stream) {
    const float* x  = (const float*)d_in[0];
    const int*   ei = (const int*)d_in[1];
    const float* ea = (const float*)d_in[2];

    const int N = in_sizes[0] / 3;
    const int E = in_sizes[2] / 3;
    const int* src = ei;
    const int* dst = ei + E;

    const float* g1 = (const float*)d_in[3];  const float* mu1 = (const float*)d_in[4];
    const float* s1 = (const float*)d_in[5];  const float* r1  = (const float*)d_in[6];
    const float* b1 = (const float*)d_in[7];
    const float* g2 = (const float*)d_in[8];  const float* mu2 = (const float*)d_in[9];
    const float* s2 = (const float*)d_in[10]; const float* r2  = (const float*)d_in[11];
    const float* b2 = (const float*)d_in[12];
    const float* g3 = (const float*)d_in[13]; const float* mu3 = (const float*)d_in[14];
    const float* s3 = (const float*)d_in[15]; const float* r3  = (const float*)d_in[16];
    const float* b3 = (const float*)d_in[17];
    const float* g4 = (const float*)d_in[18]; const float* mu4 = (const float*)d_in[19];
    const float* s4 = (const float*)d_in[20]; const float* r4  = (const float*)d_in[21];
    const float* b4 = (const float*)d_in[22];

    const int NB = (N + 63) >> 6;                   // 64-node bins
    const int P  = (N + CHUNK - 1) / CHUNK;         // scan blocks

    char* w = (char*)d_ws;
    int* cnt      = (int*)w;                         // N (also fallback cursor)
    int* rowptr   = cnt + N;                         // N+1
    int* partials = rowptr + (N + 1);                // <=1024
    int* binCur   = partials + 1024;                 // NB
    size_t off = (((size_t)(2 * N + 1) + 1024 + NB) * 4 + 15) & ~(size_t)15;

    // two-pass layout: tmp[E] + perm[E] + hA + hB
    size_t need2 = off + 2 * (size_t)E * 16 + 2 * (size_t)N * 16 * 4;
    bool twopass = ws_size >= need2;

    float4* tmp  = (float4*)(w + off);               // E (two-pass only)
    float4* perm = twopass ? (tmp + E) : tmp;        // E
    float* hA = (float*)(perm + E);                  // N*16
    float* hB = hA + (size_t)N * 16;                 // N*16

    // CSR build
    hipMemsetAsync(cnt, 0, (size_t)N * sizeof(int), stream);
    count_kernel<<<(E + TPB - 1) / TPB, TPB, 0, stream>>>(dst, cnt, E);
    partial_kernel<<<P, TPB, 0, stream>>>(cnt, partials, N);
    scan_partials_kernel<<<1, 1024, 0, stream>>>(partials, P);
    rowptr_kernel<<<P, TPB, 0, stream>>>(cnt, partials, rowptr, cnt, N, E);  // cnt becomes cursor

    if (twopass) {
        bincur_kernel<<<(NB + TPB - 1) / TPB, TPB, 0, stream>>>(rowptr, binCur, NB, N);
        pass1_kernel<<<(E + TPB - 1) / TPB, TPB, 0, stream>>>(src, dst, ea, binCur, tmp, E);
        pass2_kernel<<<NB, TPB, 0, stream>>>(rowptr, tmp, perm, N);
    } else {
        fill_kernel<<<(E + TPB - 1) / TPB, TPB, 0, stream>>>(src, dst, ea, cnt, perm, E);
    }

    float* out = (float*)d_out;

    launch_layer<3, 8, true >(x,  g1, mu1, s1, r1, b1, rowptr, perm, hA, N, stream);
    launch_layer<8, 16, true >(hA, g2, mu2, s2, r2, b2, rowptr, perm, hB, N, stream);
    launch_layer<16, 8, true >(hB, g3, mu3, s3, r3, b3, rowptr, perm, hA, N, stream);
    launch_layer<8, 4, false>(hA, g4, mu4, s4, r4, b4, rowptr, perm, out, N, stream);
}

// Round 6
// 566.236 us; speedup vs baseline: 1.5118x; 1.5118x over previous
//
#include <hip/hip_runtime.h>
#include <math.h>

#define TPB 256
#define CHUNK 1024   // elements per scan block

// ---------------------------------------------------------------------------
// Phase 0: CSR-by-dst build (once per call, shared by all 4 layers)
// ---------------------------------------------------------------------------
__global__ void count_kernel(const int* __restrict__ dst, int* __restrict__ cnt, int E) {
    int e = blockIdx.x * blockDim.x + threadIdx.x;
    if (e < E) atomicAdd(&cnt[dst[e]], 1);
}

__global__ void partial_kernel(const int* __restrict__ cnt, int* __restrict__ partials, int N) {
    __shared__ int red[TPB];
    int base = blockIdx.x * CHUNK;
    int t = threadIdx.x;
    int s = 0;
    for (int i = t; i < CHUNK; i += TPB) {
        int idx = base + i;
        if (idx < N) s += cnt[idx];
    }
    red[t] = s;
    __syncthreads();
    for (int off = TPB / 2; off > 0; off >>= 1) {
        if (t < off) red[t] += red[t + off];
        __syncthreads();
    }
    if (t == 0) partials[blockIdx.x] = red[0];
}

__global__ void scan_partials_kernel(int* __restrict__ partials, int P) {
    __shared__ int buf[1024];
    int t = threadIdx.x;
    int v = (t < P) ? partials[t] : 0;
    buf[t] = v;
    __syncthreads();
    for (int off = 1; off < 1024; off <<= 1) {
        int u = (t >= off) ? buf[t - off] : 0;
        __syncthreads();
        buf[t] += u;
        __syncthreads();
    }
    if (t < P) partials[t] = buf[t] - v;   // exclusive
}

// writes rowptr AND a cursor copy (cursor consumed by fill_kernel)
__global__ void rowptr_kernel(const int* __restrict__ cnt, const int* __restrict__ partials,
                              int* __restrict__ rowptr, int* __restrict__ cursor, int N, int E) {
    __shared__ int tsum[TPB];
    int base = blockIdx.x * CHUNK;
    int t = threadIdx.x;
    int idx0 = base + t * 4;
    int c[4];
    int s = 0;
#pragma unroll
    for (int j = 0; j < 4; ++j) {
        int i = idx0 + j;
        c[j] = (i < N) ? cnt[i] : 0;
        s += c[j];
    }
    tsum[t] = s;
    __syncthreads();
    for (int off = 1; off < TPB; off <<= 1) {
        int u = (t >= off) ? tsum[t - off] : 0;
        __syncthreads();
        tsum[t] += u;
        __syncthreads();
    }
    int run = partials[blockIdx.x] + tsum[t] - s;
#pragma unroll
    for (int j = 0; j < 4; ++j) {
        int i = idx0 + j;
        if (i < N) { rowptr[i] = run; cursor[i] = run; run += c[j]; }
    }
    if (blockIdx.x == 0 && t == 0) rowptr[N] = E;
}

// single-pass dst-bucketed scatter: record = {ea0, ea1, ea2, uint src}
__global__ void fill_kernel(const int* __restrict__ src, const int* __restrict__ dst,
                            const float* __restrict__ ea, int* __restrict__ cursor,
                            float4* __restrict__ perm, int E) {
    int e = blockIdx.x * blockDim.x + threadIdx.x;
    if (e >= E) return;
    int d = dst[e];
    int pos = atomicAdd(&cursor[d], 1);
    float4 p;
    p.x = ea[(size_t)e * 3 + 0];
    p.y = ea[(size_t)e * 3 + 1];
    p.z = ea[(size_t)e * 3 + 2];
    p.w = __uint_as_float((unsigned)src[e]);
    perm[pos] = p;
}

// ---------------------------------------------------------------------------
// Fused layer: 4 lanes per node. Sufficient statistic T[i][k] = sum_e w_k * h[src][i],
// then out[n,o] = elu( invdeg * sum_{i,k} T[i][k] g[i][k*COUT+o] + h[n]@root + b ).
// ---------------------------------------------------------------------------
template<int CIN, int COUT, bool ELU>
__global__ void layer_kernel(const float* __restrict__ h,
                             const float* __restrict__ g,      // [CIN, 3*COUT]
                             const float* __restrict__ mu, const float* __restrict__ sigma,
                             const float* __restrict__ root,   // [CIN, COUT]
                             const float* __restrict__ bias,
                             const int* __restrict__ rowptr,
                             const float4* __restrict__ perm,
                             float* __restrict__ out, int N) {
    __shared__ float s_g[CIN * 3 * COUT];
    __shared__ float s_root[CIN * COUT];
    __shared__ float s_b[COUT];
    __shared__ float s_mu[9], s_gs[9];
    int t = threadIdx.x;
    for (int i = t; i < CIN * 3 * COUT; i += TPB) s_g[i] = g[i];
    for (int i = t; i < CIN * COUT; i += TPB) s_root[i] = root[i];
    if (t < COUT) s_b[t] = bias[t];
    if (t < 9) {
        s_mu[t] = mu[t];
        float sg = sigma[t];
        s_gs[t] = -0.5f / (1e-15f + sg * sg);
    }
    __syncthreads();

    int gid = blockIdx.x * TPB + t;
    int n = gid >> 2;
    int sub = gid & 3;
    bool active = n < N;

    float T[CIN][3] = {};
    int e0 = 0, e1 = 0;
    if (active) { e0 = rowptr[n]; e1 = rowptr[n + 1]; }

    for (int e = e0 + sub; e < e1; e += 4) {
        float4 p = perm[e];
        unsigned s = __float_as_uint(p.w);
        float w[3];
#pragma unroll
        for (int k = 0; k < 3; ++k) {
            float d0 = p.x - s_mu[3 * k + 0];
            float d1 = p.y - s_mu[3 * k + 1];
            float d2 = p.z - s_mu[3 * k + 2];
            w[k] = __expf(d0 * d0 * s_gs[3 * k + 0] +
                          d1 * d1 * s_gs[3 * k + 1] +
                          d2 * d2 * s_gs[3 * k + 2]);
        }
        const float* hr = h + (size_t)s * CIN;
        float hv[CIN];
        if constexpr (CIN == 3) {
            hv[0] = hr[0]; hv[1] = hr[1]; hv[2] = hr[2];
        } else {
#pragma unroll
            for (int q = 0; q < CIN / 4; ++q) {
                float4 v = ((const float4*)hr)[q];
                hv[4 * q + 0] = v.x; hv[4 * q + 1] = v.y;
                hv[4 * q + 2] = v.z; hv[4 * q + 3] = v.w;
            }
        }
#pragma unroll
        for (int i = 0; i < CIN; ++i) {
            T[i][0] = fmaf(hv[i], w[0], T[i][0]);
            T[i][1] = fmaf(hv[i], w[1], T[i][1]);
            T[i][2] = fmaf(hv[i], w[2], T[i][2]);
        }
    }

    // reduce T across the 4 lanes of this node (lanes consecutive: xor 1, 2)
#pragma unroll
    for (int i = 0; i < CIN; ++i)
#pragma unroll
        for (int k = 0; k < 3; ++k) {
            float v = T[i][k];
            v += __shfl_xor(v, 1);
            v += __shfl_xor(v, 2);
            T[i][k] = v;
        }

    if (active) {
        float invd = 1.0f / fmaxf((float)(e1 - e0), 1.0f);
        const float* hn = h + (size_t)n * CIN;
        float hv2[CIN];
        if constexpr (CIN == 3) {
            hv2[0] = hn[0]; hv2[1] = hn[1]; hv2[2] = hn[2];
        } else {
#pragma unroll
            for (int q = 0; q < CIN / 4; ++q) {
                float4 v = ((const float4*)hn)[q];
                hv2[4 * q + 0] = v.x; hv2[4 * q + 1] = v.y;
                hv2[4 * q + 2] = v.z; hv2[4 * q + 3] = v.w;
            }
        }
#pragma unroll
        for (int j = 0; j < COUT / 4; ++j) {
            int o = sub + 4 * j;
            float acc = 0.f;
#pragma unroll
            for (int i = 0; i < CIN; ++i)
#pragma unroll
                for (int k = 0; k < 3; ++k)
                    acc = fmaf(T[i][k], s_g[(i * 3 + k) * COUT + o], acc);
            acc = acc * invd + s_b[o];
#pragma unroll
            for (int i = 0; i < CIN; ++i)
                acc = fmaf(hv2[i], s_root[i * COUT + o], acc);
            if (ELU && acc < 0.f) acc = __expf(acc) - 1.0f;
            out[(size_t)n * COUT + o] = acc;
        }
    }
}

// ---------------------------------------------------------------------------
template<int CIN, int COUT, bool ELU>
static void launch_layer(const float* hin, const float* g, const float* mu,
                         const float* sigma, const float* root, const float* b,
                         const int* rowptr, const float4* perm,
                         float* hout, int N, hipStream_t stream) {
    int blocks = (N * 4 + TPB - 1) / TPB;
    layer_kernel<CIN, COUT, ELU><<<blocks, TPB, 0, stream>>>(
        hin, g, mu, sigma, root, b, rowptr, perm, hout, N);
}

extern "C" void kernel_launch(void* const* d_in, const int* in_sizes, int n_in,
                              void* d_out, int out_size, void* d_ws, size_t ws_size,
                              hipStream_t stream) {
    const float* x  = (const float*)d_in[0];
    const int*   ei = (const int*)d_in[1];
    const float* ea = (const float*)d_in[2];

    const int N = in_sizes[0] / 3;
    const int E = in_sizes[2] / 3;
    const int* src = ei;
    const int* dst = ei + E;

    const float* g1 = (const float*)d_in[3];  const float* mu1 = (const float*)d_in[4];
    const float* s1 = (const float*)d_in[5];  const float* r1  = (const float*)d_in[6];
    const float* b1 = (const float*)d_in[7];
    const float* g2 = (const float*)d_in[8];  const float* mu2 = (const float*)d_in[9];
    const float* s2 = (const float*)d_in[10]; const float* r2  = (const float*)d_in[11];
    const float* b2 = (const float*)d_in[12];
    const float* g3 = (const float*)d_in[13]; const float* mu3 = (const float*)d_in[14];
    const float* s3 = (const float*)d_in[15]; const float* r3  = (const float*)d_in[16];
    const float* b3 = (const float*)d_in[17];
    const float* g4 = (const float*)d_in[18]; const float* mu4 = (const float*)d_in[19];
    const float* s4 = (const float*)d_in[20]; const float* r4  = (const float*)d_in[21];
    const float* b4 = (const float*)d_in[22];

    const int P = (N + CHUNK - 1) / CHUNK;           // scan blocks

    char* w = (char*)d_ws;
    int* cnt      = (int*)w;                          // N (count, then fill cursor)
    int* rowptr   = cnt + N;                          // N+1
    int* partials = rowptr + (N + 1);                 // <=1024
    size_t off = (((size_t)(2 * N + 1) + 1024) * 4 + 15) & ~(size_t)15;
    float4* perm = (float4*)(w + off);                // E
    float* hA = (float*)(perm + E);                   // N*16
    float* hB = hA + (size_t)N * 16;                  // N*16

    // CSR build + single-pass dst-bucketed scatter
    hipMemsetAsync(cnt, 0, (size_t)N * sizeof(int), stream);
    count_kernel<<<(E + TPB - 1) / TPB, TPB, 0, stream>>>(dst, cnt, E);
    partial_kernel<<<P, TPB, 0, stream>>>(cnt, partials, N);
    scan_partials_kernel<<<1, 1024, 0, stream>>>(partials, P);
    rowptr_kernel<<<P, TPB, 0, stream>>>(cnt, partials, rowptr, cnt, N, E);  // cnt -> cursor
    fill_kernel<<<(E + TPB - 1) / TPB, TPB, 0, stream>>>(src, dst, ea, cnt, perm, E);

    float* out = (float*)d_out;

    launch_layer<3, 8, true >(x,  g1, mu1, s1, r1, b1, rowptr, perm, hA, N, stream);
    launch_layer<8, 16, true >(hA, g2, mu2, s2, r2, b2, rowptr, perm, hB, N, stream);
    launch_layer<16, 8, true >(hB, g3, mu3, s3, r3, b3, rowptr, perm, hA, N, stream);
    launch_layer<8, 4, false>(hA, g4, mu4, s4, r4, b4, rowptr, perm, out, N, stream);
}

// Round 7
// 346.863 us; speedup vs baseline: 2.4680x; 1.6324x over previous
//
#include <hip/hip_runtime.h>
#include <math.h>

#define TPB 256
#define BIG 1024          // threads for hist/scatter kernels
#define G_CHUNKS 256      // edge chunks (one workgroup each in A and C)
#define NBCAP 2048        // max bins supported by LDS arrays (N <= 131072)
#define SCAP 3584         // max records staged per bin in D (57KB LDS)

// ===========================================================================
// Counting sort of edges by dst, bin = dst>>6 (64 nodes per bin).
// record float4 = {ea0, ea1, ea2, uint bits}; bits = (rel<<26)|src in tmp,
// src only in perm.
// ===========================================================================

// A: per-chunk LDS histogram -> hist[b*G + g]
__global__ void histA_kernel(const int* __restrict__ dst, int* __restrict__ hist,
                             int E, int CE, int NB) {
    __shared__ int lh[NBCAP];
    int g = blockIdx.x, t = threadIdx.x;
    for (int b = t; b < NBCAP; b += BIG) lh[b] = 0;
    __syncthreads();
    int e0 = g * CE, e1 = min(e0 + CE, E);
    for (int e = e0 + t; e < e1; e += BIG) atomicAdd(&lh[dst[e] >> 6], 1);
    __syncthreads();
    for (int b = t; b < NB; b += BIG) hist[b * G_CHUNKS + g] = lh[b];
}

// B1: single-block scan over per-bin totals -> binstart[NB+1]
__global__ void binscan_kernel(const int* __restrict__ hist, int* __restrict__ binstart,
                               int NB) {
    __shared__ int buf[NBCAP];
    int t = threadIdx.x;                       // 1024 threads
    int b0 = t, b1 = t + 1024;
    int s0 = 0, s1 = 0;
    if (b0 < NB) for (int g = 0; g < G_CHUNKS; ++g) s0 += hist[b0 * G_CHUNKS + g];
    if (b1 < NB) for (int g = 0; g < G_CHUNKS; ++g) s1 += hist[b1 * G_CHUNKS + g];
    buf[b0] = s0; buf[b1] = s1;
    __syncthreads();
    for (int off = 1; off < NBCAP; off <<= 1) {
        int a0 = buf[b0], m0 = (b0 >= off) ? buf[b0 - off] : 0;
        int a1 = buf[b1], m1 = (b1 >= off) ? buf[b1 - off] : 0;
        __syncthreads();
        buf[b0] = a0 + m0; buf[b1] = a1 + m1;
        __syncthreads();
    }
    if (b0 < NB) binstart[b0] = buf[b0] - s0;
    if (b1 < NB) binstart[b1] = buf[b1] - s1;
    if (t == 1023) binstart[NB] = buf[NBCAP - 1];   // = E
}

// B2: per-bin exclusive scan over chunks: hist[b][g] := global base of slice (b,g)
__global__ void base_kernel(int* __restrict__ hist, const int* __restrict__ binstart,
                            int NB) {
    int b = blockIdx.x * TPB + threadIdx.x;
    if (b >= NB) return;
    int run = binstart[b];
    for (int g = 0; g < G_CHUNKS; ++g) {
        int c = hist[b * G_CHUNKS + g];
        hist[b * G_CHUNKS + g] = run;
        run += c;
    }
}

// C: scatter records into exclusive (bin,chunk) slices via LDS cursors.
__global__ void scatterC_kernel(const int* __restrict__ src, const int* __restrict__ dst,
                                const float* __restrict__ ea, const int* __restrict__ hist,
                                float4* __restrict__ tmp, int E, int CE, int NB) {
    __shared__ int lcur[NBCAP];
    int g = blockIdx.x, t = threadIdx.x;
    for (int b = t; b < NB; b += BIG) lcur[b] = hist[b * G_CHUNKS + g];
    __syncthreads();
    int e0 = g * CE, e1 = min(e0 + CE, E);
    for (int e = e0 + t; e < e1; e += BIG) {
        int d = dst[e];
        int pos = atomicAdd(&lcur[d >> 6], 1);
        float4 p;
        p.x = ea[(size_t)e * 3 + 0];
        p.y = ea[(size_t)e * 3 + 1];
        p.z = ea[(size_t)e * 3 + 2];
        p.w = __uint_as_float((unsigned)src[e] | ((unsigned)(d & 63) << 26));
        tmp[pos] = p;
    }
}

// D: per-bin sort by rel-node through LDS staging; coalesced output; emits rowptr.
__global__ void binsortD_kernel(const float4* __restrict__ tmp,
                                const int* __restrict__ binstart,
                                float4* __restrict__ perm, int* __restrict__ rowptr,
                                int N, int NB) {
    __shared__ float4 stage[SCAP];
    __shared__ int h64[64], lcur[64];
    int b = blockIdx.x, t = threadIdx.x;      // TPB = 256
    int lo = binstart[b], hi = binstart[b + 1];
    int cnt = hi - lo;
    if (t < 64) h64[t] = 0;
    __syncthreads();
    for (int i = lo + t; i < hi; i += TPB) {
        unsigned bits = __float_as_uint(tmp[i].w);
        atomicAdd(&h64[bits >> 26], 1);
    }
    __syncthreads();
    if (t == 0) {
        int run = 0;
        for (int r = 0; r < 64; ++r) { int c = h64[r]; lcur[r] = run; run += c; }
    }
    __syncthreads();
    int n0 = b << 6;
    if (t < 64 && n0 + t < N) rowptr[n0 + t] = lo + lcur[t];
    if (b == NB - 1 && t == 64) rowptr[N] = hi;
    __syncthreads();                          // rowptr reads before cursor mutation
    if (cnt <= SCAP) {
        for (int i = lo + t; i < hi; i += TPB) {
            float4 v = tmp[i];
            unsigned bits = __float_as_uint(v.w);
            int pos = atomicAdd(&lcur[bits >> 26], 1);
            v.w = __uint_as_float(bits & 0x03FFFFFFu);
            stage[pos] = v;
        }
        __syncthreads();
        for (int j = t; j < cnt; j += TPB) perm[lo + j] = stage[j];
    } else {                                  // overflow fallback (never for this input)
        for (int i = lo + t; i < hi; i += TPB) {
            float4 v = tmp[i];
            unsigned bits = __float_as_uint(v.w);
            int pos = atomicAdd(&lcur[bits >> 26], 1);
            v.w = __uint_as_float(bits & 0x03FFFFFFu);
            perm[lo + pos] = v;
        }
    }
}

// ===========================================================================
// Fused layer (unchanged from validated R6): 4 lanes per node, sufficient
// statistic T[i][k] = sum_e w_k(e) * h[src_e][i].
// ===========================================================================
template<int CIN, int COUT, bool ELU>
__global__ void layer_kernel(const float* __restrict__ h,
                             const float* __restrict__ g,      // [CIN, 3*COUT]
                             const float* __restrict__ mu, const float* __restrict__ sigma,
                             const float* __restrict__ root,   // [CIN, COUT]
                             const float* __restrict__ bias,
                             const int* __restrict__ rowptr,
                             const float4* __restrict__ perm,
                             float* __restrict__ out, int N) {
    __shared__ float s_g[CIN * 3 * COUT];
    __shared__ float s_root[CIN * COUT];
    __shared__ float s_b[COUT];
    __shared__ float s_mu[9], s_gs[9];
    int t = threadIdx.x;
    for (int i = t; i < CIN * 3 * COUT; i += TPB) s_g[i] = g[i];
    for (int i = t; i < CIN * COUT; i += TPB) s_root[i] = root[i];
    if (t < COUT) s_b[t] = bias[t];
    if (t < 9) {
        s_mu[t] = mu[t];
        float sg = sigma[t];
        s_gs[t] = -0.5f / (1e-15f + sg * sg);
    }
    __syncthreads();

    int gid = blockIdx.x * TPB + t;
    int n = gid >> 2;
    int sub = gid & 3;
    bool active = n < N;

    float T[CIN][3] = {};
    int e0 = 0, e1 = 0;
    if (active) { e0 = rowptr[n]; e1 = rowptr[n + 1]; }

    for (int e = e0 + sub; e < e1; e += 4) {
        float4 p = perm[e];
        unsigned s = __float_as_uint(p.w);
        float w[3];
#pragma unroll
        for (int k = 0; k < 3; ++k) {
            float d0 = p.x - s_mu[3 * k + 0];
            float d1 = p.y - s_mu[3 * k + 1];
            float d2 = p.z - s_mu[3 * k + 2];
            w[k] = __expf(d0 * d0 * s_gs[3 * k + 0] +
                          d1 * d1 * s_gs[3 * k + 1] +
                          d2 * d2 * s_gs[3 * k + 2]);
        }
        const float* hr = h + (size_t)s * CIN;
        float hv[CIN];
        if constexpr (CIN == 3) {
            hv[0] = hr[0]; hv[1] = hr[1]; hv[2] = hr[2];
        } else {
#pragma unroll
            for (int q = 0; q < CIN / 4; ++q) {
                float4 v = ((const float4*)hr)[q];
                hv[4 * q + 0] = v.x; hv[4 * q + 1] = v.y;
                hv[4 * q + 2] = v.z; hv[4 * q + 3] = v.w;
            }
        }
#pragma unroll
        for (int i = 0; i < CIN; ++i) {
            T[i][0] = fmaf(hv[i], w[0], T[i][0]);
            T[i][1] = fmaf(hv[i], w[1], T[i][1]);
            T[i][2] = fmaf(hv[i], w[2], T[i][2]);
        }
    }

#pragma unroll
    for (int i = 0; i < CIN; ++i)
#pragma unroll
        for (int k = 0; k < 3; ++k) {
            float v = T[i][k];
            v += __shfl_xor(v, 1);
            v += __shfl_xor(v, 2);
            T[i][k] = v;
        }

    if (active) {
        float invd = 1.0f / fmaxf((float)(e1 - e0), 1.0f);
        const float* hn = h + (size_t)n * CIN;
        float hv2[CIN];
        if constexpr (CIN == 3) {
            hv2[0] = hn[0]; hv2[1] = hn[1]; hv2[2] = hn[2];
        } else {
#pragma unroll
            for (int q = 0; q < CIN / 4; ++q) {
                float4 v = ((const float4*)hn)[q];
                hv2[4 * q + 0] = v.x; hv2[4 * q + 1] = v.y;
                hv2[4 * q + 2] = v.z; hv2[4 * q + 3] = v.w;
            }
        }
#pragma unroll
        for (int j = 0; j < COUT / 4; ++j) {
            int o = sub + 4 * j;
            float acc = 0.f;
#pragma unroll
            for (int i = 0; i < CIN; ++i)
#pragma unroll
                for (int k = 0; k < 3; ++k)
                    acc = fmaf(T[i][k], s_g[(i * 3 + k) * COUT + o], acc);
            acc = acc * invd + s_b[o];
#pragma unroll
            for (int i = 0; i < CIN; ++i)
                acc = fmaf(hv2[i], s_root[i * COUT + o], acc);
            if (ELU && acc < 0.f) acc = __expf(acc) - 1.0f;
            out[(size_t)n * COUT + o] = acc;
        }
    }
}

template<int CIN, int COUT, bool ELU>
static void launch_layer(const float* hin, const float* g, const float* mu,
                         const float* sigma, const float* root, const float* b,
                         const int* rowptr, const float4* perm,
                         float* hout, int N, hipStream_t stream) {
    int blocks = (N * 4 + TPB - 1) / TPB;
    layer_kernel<CIN, COUT, ELU><<<blocks, TPB, 0, stream>>>(
        hin, g, mu, sigma, root, b, rowptr, perm, hout, N);
}

// ---------------------------------------------------------------------------
extern "C" void kernel_launch(void* const* d_in, const int* in_sizes, int n_in,
                              void* d_out, int out_size, void* d_ws, size_t ws_size,
                              hipStream_t stream) {
    const float* x  = (const float*)d_in[0];
    const int*   ei = (const int*)d_in[1];
    const float* ea = (const float*)d_in[2];

    const int N = in_sizes[0] / 3;
    const int E = in_sizes[2] / 3;
    const int* src = ei;
    const int* dst = ei + E;

    const float* g1 = (const float*)d_in[3];  const float* mu1 = (const float*)d_in[4];
    const float* s1 = (const float*)d_in[5];  const float* r1  = (const float*)d_in[6];
    const float* b1 = (const float*)d_in[7];
    const float* g2 = (const float*)d_in[8];  const float* mu2 = (const float*)d_in[9];
    const float* s2 = (const float*)d_in[10]; const float* r2  = (const float*)d_in[11];
    const float* b2 = (const float*)d_in[12];
    const float* g3 = (const float*)d_in[13]; const float* mu3 = (const float*)d_in[14];
    const float* s3 = (const float*)d_in[15]; const float* r3  = (const float*)d_in[16];
    const float* b3 = (const float*)d_in[17];
    const float* g4 = (const float*)d_in[18]; const float* mu4 = (const float*)d_in[19];
    const float* s4 = (const float*)d_in[20]; const float* r4  = (const float*)d_in[21];
    const float* b4 = (const float*)d_in[22];

    const int NB = (N + 63) >> 6;                    // 64-node bins (1563 for N=100K)
    const int CE = (E + G_CHUNKS - 1) / G_CHUNKS;    // edges per chunk

    // workspace: [rowptr N+1][binstart NB+1] | tmp[E] perm[E] | hA hB (hist aliases hB)
    char* w = (char*)d_ws;
    int* rowptr   = (int*)w;                          // N+1
    int* binstart = rowptr + (N + 1);                 // NB+1
    size_t off = (((size_t)(N + 1 + NB + 1)) * 4 + 15) & ~(size_t)15;
    float4* tmp  = (float4*)(w + off);                // E
    float4* perm = tmp + E;                           // E
    float* hA = (float*)(perm + E);                   // N*16
    float* hB = hA + (size_t)N * 16;                  // N*16
    int* hist = (int*)hB;                             // NB*G ints (1.6MB), dead once layers run

    // counting sort by dst (no global atomics) + rowptr
    histA_kernel<<<G_CHUNKS, BIG, 0, stream>>>(dst, hist, E, CE, NB);
    binscan_kernel<<<1, BIG, 0, stream>>>(hist, binstart, NB);
    base_kernel<<<(NB + TPB - 1) / TPB, TPB, 0, stream>>>(hist, binstart, NB);
    scatterC_kernel<<<G_CHUNKS, BIG, 0, stream>>>(src, dst, ea, hist, tmp, E, CE, NB);
    binsortD_kernel<<<NB, TPB, 0, stream>>>(tmp, binstart, perm, rowptr, N, NB);

    float* out = (float*)d_out;

    launch_layer<3, 8, true >(x,  g1, mu1, s1, r1, b1, rowptr, perm, hA, N, stream);
    launch_layer<8, 16, true >(hA, g2, mu2, s2, r2, b2, rowptr, perm, hB, N, stream);
    launch_layer<16, 8, true >(hB, g3, mu3, s3, r3, b3, rowptr, perm, hA, N, stream);
    launch_layer<8, 4, false>(hA, g4, mu4, s4, r4, b4, rowptr, perm, out, N, stream);
}